// Round 18
// baseline (81.278 us; speedup 1.0000x reference)
//
#include <hip/hip_runtime.h>

typedef short bf16x8 __attribute__((ext_vector_type(8)));
typedef float f32x4 __attribute__((ext_vector_type(4)));

__device__ __forceinline__ unsigned short f2bf(float f) {
  unsigned int x = __float_as_uint(f);
  x += 0x7fffu + ((x >> 16) & 1u);
  return (unsigned short)(x >> 16);
}
__device__ __forceinline__ float bf2f(unsigned short u) {
  return __uint_as_float(((unsigned int)u) << 16);
}

// rocPRIM-pattern wave64 sum via DPP (VALU-only, no LDS pipe). Sum -> lane 63.
__device__ __forceinline__ float dpp_add(float x) {
  x += __int_as_float(__builtin_amdgcn_update_dpp(0, __float_as_int(x), 0x111, 0xf, 0xf, false)); // row_shr:1
  x += __int_as_float(__builtin_amdgcn_update_dpp(0, __float_as_int(x), 0x112, 0xf, 0xf, false)); // row_shr:2
  x += __int_as_float(__builtin_amdgcn_update_dpp(0, __float_as_int(x), 0x114, 0xf, 0xe, false)); // row_shr:4
  x += __int_as_float(__builtin_amdgcn_update_dpp(0, __float_as_int(x), 0x118, 0xf, 0xc, false)); // row_shr:8
  x += __int_as_float(__builtin_amdgcn_update_dpp(0, __float_as_int(x), 0x142, 0xa, 0xf, false)); // row_bcast:15
  x += __int_as_float(__builtin_amdgcn_update_dpp(0, __float_as_int(x), 0x143, 0xc, 0xf, false)); // row_bcast:31
  return x;
}

#define GLD_LDS16(gp, lp)                                                     \
  __builtin_amdgcn_global_load_lds(                                           \
      (const __attribute__((address_space(1))) void*)(gp),                    \
      (__attribute__((address_space(3))) void*)(lp), 16, 0, 0)

// ---------------------------------------------------------------------------
// K0 (blocks 0..1023): W_sub f32 [k][n] -> Wt bf16 [n][k] transpose (first).
// K1 (blocks 1024..9215): per-(b,s) LN stats + h_avg (bf16) + beta GEMV.
// (R10-proven — FROZEN. Measured R14: 21.9 µs ≈ HBM floor.)
// ---------------------------------------------------------------------------
__global__ __launch_bounds__(256) void k_pre(
    const float* __restrict__ h,       // (8192, 4, 1024)
    const float* __restrict__ ln_g,    // (1024)
    const float* __restrict__ ln_b,    // (1024)
    const float* __restrict__ dbf,     // (1024, 4)
    const float* __restrict__ dbs,     // (1)
    const float* __restrict__ sbeta,   // (4)
    const float* __restrict__ W,       // (1024, 1024)
    unsigned short* __restrict__ havg, // (8192, 1024) bf16
    float* __restrict__ beta_out,      // (8192, 4)
    unsigned short* __restrict__ Wt)   // (1024, 1024) bf16 transposed
{
  __shared__ float shmem[32 * 33];
  const int t = threadIdx.x;

  if (blockIdx.x < 1024) {
    // ---- W transpose (runs first) ----
    const int b = blockIdx.x;
    const int bn = b & 31, bk = b >> 5;
    float (*tile)[33] = (float (*)[33])shmem;
    const int tx = t & 31, ty = t >> 5;
#pragma unroll
    for (int r = ty; r < 32; r += 8)
      tile[r][tx] = W[(size_t)(bk * 32 + r) * 1024 + bn * 32 + tx];
    __syncthreads();
#pragma unroll
    for (int r = ty; r < 32; r += 8)
      Wt[(size_t)(bn * 32 + r) * 1024 + bk * 32 + tx] = f2bf(tile[tx][r]);
    return;
  }

  const int bs = blockIdx.x - 1024;
  const int lane = t & 63, wid = t >> 6;
  float (*sm)[8] = (float (*)[8])shmem;
  const float* hrow = h + (size_t)bs * 4096;
  const int d0 = t * 4;

  float x[4][4];
  float red[8];
#pragma unroll
  for (int n = 0; n < 4; ++n) {
    float4 v = *(const float4*)(hrow + n * 1024 + d0);
    x[n][0] = v.x; x[n][1] = v.y; x[n][2] = v.z; x[n][3] = v.w;
    red[n] = v.x + v.y + v.z + v.w;
    red[4 + n] = v.x * v.x + v.y * v.y + v.z * v.z + v.w * v.w;
  }
#pragma unroll
  for (int k = 0; k < 8; ++k) red[k] = dpp_add(red[k]);
  if (lane == 63) {
#pragma unroll
    for (int k = 0; k < 8; ++k) sm[wid][k] = red[k];
  }
  __syncthreads();
  float mean[4], rstd[4];
#pragma unroll
  for (int n = 0; n < 4; ++n) {
    float s = sm[0][n] + sm[1][n] + sm[2][n] + sm[3][n];
    float sq = sm[0][4 + n] + sm[1][4 + n] + sm[2][4 + n] + sm[3][4 + n];
    float m = s * (1.0f / 1024.0f);
    float var = sq * (1.0f / 1024.0f) - m * m;
    mean[n] = m;
    rstd[n] = rsqrtf(var + 1e-5f);
  }
  const float4 g4 = *(const float4*)(ln_g + d0);
  const float4 b4 = *(const float4*)(ln_b + d0);
  const float gg[4] = {g4.x, g4.y, g4.z, g4.w};
  const float bb[4] = {b4.x, b4.y, b4.z, b4.w};

  float nm[4];
  ushort4 pack;
  unsigned short* pk = (unsigned short*)&pack;
#pragma unroll
  for (int j = 0; j < 4; ++j) {
    float sh = 0.f, sn = 0.f;
#pragma unroll
    for (int n = 0; n < 4; ++n) {
      sh += x[n][j];
      sn += (x[n][j] - mean[n]) * rstd[n];
    }
    pk[j] = f2bf(0.25f * sh);               // h_avg = mix_h row (i-independent)
    nm[j] = 0.25f * sn * gg[j] + bb[j];     // norm_h_mean
  }
  *(ushort4*)(havg + (size_t)bs * 1024 + d0) = pack;

  // beta = tanh(nm @ dbf) * scale + static_beta
  float a4[4] = {0.f, 0.f, 0.f, 0.f};
#pragma unroll
  for (int j = 0; j < 4; ++j) {
    const float4 w = *(const float4*)(dbf + (size_t)(d0 + j) * 4);
    a4[0] += nm[j] * w.x; a4[1] += nm[j] * w.y;
    a4[2] += nm[j] * w.z; a4[3] += nm[j] * w.w;
  }
#pragma unroll
  for (int c = 0; c < 4; ++c) a4[c] = dpp_add(a4[c]);
  __syncthreads();  // all stats reads done before sm re-write
  if (lane == 63) {
#pragma unroll
    for (int c = 0; c < 4; ++c) sm[wid][c] = a4[c];
  }
  __syncthreads();
  if (t == 0) {
    const float sc = dbs[0];
#pragma unroll
    for (int c = 0; c < 4; ++c) {
      float dot = sm[0][c] + sm[1][c] + sm[2][c] + sm[3][c];
      beta_out[(size_t)bs * 4 + c] = tanhf(dot) * sc + sbeta[c];
    }
  }
}

// ---------------------------------------------------------------------------
// K2: h_o = h_avg @ W  (M=8192, N=1024, K=1024, 128x128 tile, BK=64)
//     R10 structure BYTE-FOR-BYTE except: 56 KB LDS pad -> 88 KB total ->
//     1 block/CU residency -> the 512 blocks run as TWO sequential waves
//     per CU. Wave-1 epilogue stores drain WHILE wave-2 computes (queued-
//     block overlap — the only overlap form not yet tested; co-resident
//     lockstep blocks finish together and expose the full store burst).
//     epilogue: out[m][i][n] = beta[m][i]*h_o[m][n] + h_avg[m][n]
// ---------------------------------------------------------------------------
__global__ __launch_bounds__(256) void k_gemm_ep(
    const unsigned short* __restrict__ A,   // (8192,1024) bf16  h_avg
    const unsigned short* __restrict__ Bt,  // (1024,1024) bf16  Wt[n][k]
    const float* __restrict__ beta4,        // (8192,4)
    float* __restrict__ out)                // (8192,4,1024)
{
  __shared__ unsigned short As[2][128][32];
  __shared__ unsigned short Bs[2][128][32];
  __shared__ char occ_pad[56 * 1024];  // residency limiter: 88 KB total LDS
  const int t = threadIdx.x;
  const int wid = t >> 6, lane = t & 63;
  const int mblk = blockIdx.x, nblk = blockIdx.y;
  if (mblk > 4096) occ_pad[t] = 1;  // never true; keeps pad allocated
  const int wr = wid >> 1, wc = wid & 1;      // 2x2 waves, 64x64 each
  const int l15 = lane & 15, kg = lane >> 4;  // fragment coords

  f32x4 acc[4][4] = {};

  const int srow = t >> 2;
  const int sk8 = (t & 3) * 8;
  const unsigned short* gA = A + (size_t)(mblk * 128 + srow) * 1024 + sk8;
  const unsigned short* gB = Bt + (size_t)(nblk * 128 + srow) * 1024 + sk8;
  char* ldsA = (char*)As + wid * 1024;  // wave-uniform base
  char* ldsB = (char*)Bs + wid * 1024;

  for (int kt2 = 0; kt2 < 16; ++kt2) {
    const int ko = kt2 * 64;
    // stage BOTH 32-wide sub-tiles, then a single drain barrier
    GLD_LDS16(gA + ko, ldsA);
    GLD_LDS16(gA + 64 * 1024 + ko, ldsA + 4096);
    GLD_LDS16(gA + ko + 32, ldsA + 8192);
    GLD_LDS16(gA + 64 * 1024 + ko + 32, ldsA + 8192 + 4096);
    GLD_LDS16(gB + ko, ldsB);
    GLD_LDS16(gB + 64 * 1024 + ko, ldsB + 4096);
    GLD_LDS16(gB + ko + 32, ldsB + 8192);
    GLD_LDS16(gB + 64 * 1024 + ko + 32, ldsB + 8192 + 4096);
    __syncthreads();
#pragma unroll
    for (int sub = 0; sub < 2; ++sub) {
      bf16x8 a[4], b[4];
#pragma unroll
      for (int mi = 0; mi < 4; ++mi)
        a[mi] = *(const bf16x8*)(&As[sub][wr * 64 + mi * 16 + l15][kg * 8]);
#pragma unroll
      for (int ni = 0; ni < 4; ++ni)
        b[ni] = *(const bf16x8*)(&Bs[sub][wc * 64 + ni * 16 + l15][kg * 8]);
#pragma unroll
      for (int mi = 0; mi < 4; ++mi)
#pragma unroll
        for (int ni = 0; ni < 4; ++ni)
          acc[mi][ni] =
              __builtin_amdgcn_mfma_f32_16x16x32_bf16(a[mi], b[ni], acc[mi][ni], 0, 0, 0);
    }
    __syncthreads();
  }

  // epilogue: D row = 4*(lane>>4)+reg, col = lane&15 within each 16x16 frag
  const int rbase = mblk * 128 + wr * 64 + kg * 4;
  const int cbase = nblk * 128 + wc * 64 + l15;
#pragma unroll
  for (int mi = 0; mi < 4; ++mi) {
    float4 be[4];
#pragma unroll
    for (int r = 0; r < 4; ++r)
      be[r] = *(const float4*)(beta4 + (size_t)(rbase + mi * 16 + r) * 4);
#pragma unroll
    for (int ni = 0; ni < 4; ++ni) {
      const int col = cbase + ni * 16;
#pragma unroll
      for (int r = 0; r < 4; ++r) {
        const int row = rbase + mi * 16 + r;
        const float ho = acc[mi][ni][r];
        const float hv = bf2f(A[(size_t)row * 1024 + col]);
        const float4 bq = be[r];
        float* o = out + (size_t)row * 4096 + col;
        o[0]    = bq.x * ho + hv;
        o[1024] = bq.y * ho + hv;
        o[2048] = bq.z * ho + hv;
        o[3072] = bq.w * ho + hv;
      }
    }
  }
}

extern "C" void kernel_launch(void* const* d_in, const int* in_sizes, int n_in,
                              void* d_out, int out_size, void* d_ws, size_t ws_size,
                              hipStream_t stream) {
  const float* h     = (const float*)d_in[0];
  // d_in[1] static_alpha, d_in[3] dynamic_alpha_fn, d_in[4] dynamic_alpha_scale:
  // dead — Sinkhorn output is exactly 1/n for this broadcast-structured alpha.
  const float* sbeta = (const float*)d_in[2];
  const float* dbf   = (const float*)d_in[5];
  const float* dbs   = (const float*)d_in[6];
  const float* ln_g  = (const float*)d_in[7];
  const float* ln_b  = (const float*)d_in[8];
  const float* W     = (const float*)d_in[9];
  float* out = (float*)d_out;

  char* ws = (char*)d_ws;
  unsigned short* havg = (unsigned short*)ws;                  // 16 MB
  unsigned short* Wt   = (unsigned short*)(ws + (16u << 20));  // 2 MB
  float* beta          = (float*)(ws + (18u << 20));           // 128 KB

  hipLaunchKernelGGL(k_pre, dim3(1024 + 8192), dim3(256), 0, stream,
                     h, ln_g, ln_b, dbf, dbs, sbeta, W, havg, beta, Wt);
  hipLaunchKernelGGL(k_gemm_ep, dim3(64, 8), dim3(256), 0, stream,
                     havg, Wt, beta, out);
}